// Round 6
// baseline (5673.275 us; speedup 1.0000x reference)
//
#include <hip/hip_runtime.h>
#include <hip/hip_bf16.h>
#include <hip/hip_cooperative_groups.h>

#define B_ 1024
#define T_ 64
#define FEAT_ 1024
#define TENC_ 256
#define MAN_ 128
#define HID_ 2048
#define NG_ 8192   /* 4*HID */
#define IND_ 1408
#define CHUNK_ 21  /* 63 = 3 * 21 steps of xg precompute */

namespace cg = cooperative_groups;

typedef __attribute__((ext_vector_type(8))) short short8;
typedef __attribute__((ext_vector_type(4))) float f32x4;

typedef const __attribute__((address_space(1))) void as1_cvoid;
typedef __attribute__((address_space(3))) void as3_void;

static __device__ __forceinline__ float sigmoidf_(float x) {
  return 1.0f / (1.0f + __expf(-x));
}
static __device__ __forceinline__ float tanh_fast(float x) {
  return 1.0f - 2.0f / (__expf(2.0f * x) + 1.0f);
}
static __device__ __forceinline__ unsigned short f2b(float x) {
  __hip_bfloat16 h = __float2bfloat16(x);
  return *reinterpret_cast<unsigned short*>(&h);
}
static __device__ __forceinline__ float b2f(unsigned short u) {
  unsigned int v = ((unsigned int)u) << 16;
  return *reinterpret_cast<float*>(&v);
}

// gate permutation: new col p -> original gate-matrix row
// gate = (p>>4)&3, h = (p>>7)*32 + ((p>>6)&1)*16 + (p&15)
static __device__ __forceinline__ int gate_perm(int p) {
  int h = ((p >> 7) << 5) + (((p >> 6) & 1) << 4) + (p & 15);
  int gate = (p >> 4) & 3;
  return gate * HID_ + h;
}

__device__ __forceinline__ void gload16(const unsigned short* g, unsigned short* l) {
  __builtin_amdgcn_global_load_lds((as1_cvoid*)g, (as3_void*)l, 16, 0, 0);
}

// ---------------- small prep kernels ----------------

__global__ void zero_u32(unsigned int* p, long n) {
  long i = (long)blockIdx.x * blockDim.x + threadIdx.x;
  if (i < n) p[i] = 0u;
}

// X [b][t][f] fp32 -> Xtm [t][b][f] bf16
__global__ void pack_x_tm(const float* __restrict__ src, unsigned short* __restrict__ dst) {
  int c = threadIdx.x * 4;
  int bt = blockIdx.x;
  int b = bt >> 6, t = bt & 63;
  float4 v = *reinterpret_cast<const float4*>(&src[((long)b * T_ + t) * FEAT_ + c]);
  ushort4 o;
  o.x = f2b(v.x); o.y = f2b(v.y); o.z = f2b(v.z); o.w = f2b(v.w);
  *reinterpret_cast<ushort4*>(&dst[((long)t * B_ + b) * FEAT_ + c]) = o;
}

// fp32 (rows x cols slice) -> contiguous bf16
__global__ void pack_bf16(const float* __restrict__ src, long ld, long off,
                          unsigned short* __restrict__ dst, long cols) {
  long c = ((long)blockIdx.x * blockDim.x + threadIdx.x) * 4;
  if (c >= cols) return;
  long r = blockIdx.y;
  float4 v = *reinterpret_cast<const float4*>(&src[r * ld + off + c]);
  ushort4 o;
  o.x = f2b(v.x); o.y = f2b(v.y); o.z = f2b(v.z); o.w = f2b(v.w);
  *reinterpret_cast<ushort4*>(&dst[r * cols + c]) = o;
}

// one-pass W_ih split: row rd (gate-permuted from src), cols -> Wx | Wy | Wte (bf16)
__global__ void pack_wih(const float* __restrict__ W_ih,
                         unsigned short* __restrict__ Wx,
                         unsigned short* __restrict__ Wy,
                         unsigned short* __restrict__ Wte) {
  int c = (blockIdx.x * 256 + threadIdx.x) * 4;
  if (c >= IND_) return;
  long rd = blockIdx.y;
  long rs = gate_perm((int)rd);
  float4 v = *reinterpret_cast<const float4*>(&W_ih[rs * IND_ + c]);
  ushort4 o;
  o.x = f2b(v.x); o.y = f2b(v.y); o.z = f2b(v.z); o.w = f2b(v.w);
  if (c < FEAT_) {
    *reinterpret_cast<ushort4*>(&Wx[rd * FEAT_ + c]) = o;
  } else if (c < FEAT_ + MAN_) {
    *reinterpret_cast<ushort4*>(&Wy[rd * MAN_ + (c - FEAT_)]) = o;
  } else {
    *reinterpret_cast<ushort4*>(&Wte[rd * TENC_ + (c - FEAT_ - MAN_)]) = o;
  }
}

// WmuT[n][m] = bf16(W_mu[m][n]);  W_mu: (MAN_, HID_)
__global__ void transpose_to_bf16(const float* __restrict__ src, unsigned short* __restrict__ dst) {
  int i = blockIdx.x * 256 + threadIdx.x;       // over HID_*MAN_
  int n = i >> 7, m = i & 127;
  dst[i] = f2b(src[(long)m * HID_ + n]);
}

// permuted: bvec2[p] = (b_ih + b_hh + b_mu@Wy^T)[gate_perm(p)];  nbm[p] = -(b_mu@Wy^T)[gate_perm(p)]
__global__ void bias_prep(const float* __restrict__ W_ih, const float* __restrict__ b_ih,
                          const float* __restrict__ b_hh, const float* __restrict__ b_mu,
                          float* __restrict__ bvec2, float* __restrict__ nbm) {
  int p = blockIdx.x * 256 + threadIdx.x;
  if (p >= NG_) return;
  int g = gate_perm(p);
  const float* wy = &W_ih[(long)g * IND_ + FEAT_];
  float s = 0.f;
  #pragma unroll 8
  for (int m = 0; m < MAN_; ++m) s += b_mu[m] * wy[m];
  bvec2[p] = b_ih[g] + b_hh[g] + s;
  nbm[p] = -s;
}

__global__ void out_t0(const float* __restrict__ y0, float* __restrict__ out) {
  int i = blockIdx.x * 256 + threadIdx.x;       // over B_*MAN_
  int b = i >> 7, m = i & 127;
  out[(long)b * (T_ * MAN_) + m] = y0[i];
}

// ---------------- generic bf16 MFMA GEMM: C = A @ W^T (+bias[col]) (+addmat) ----------
// A: M x K via two K-regions (boundary K1). W: N x K via two regions, bf16 row-major.
// R2-proven structure: single LDS buffer, two barriers per K-tile, no swizzle.
// SMODE: 0 = fp32 store at out[row*ldo+col]; 1 = bf16 store; 2 = decoder scatter
//        (row -> b=row&1023, t=(row>>10)+1; out[b*T*MAN + t*MAN + col], fp32);
//        3 = fused LSTM cell: gates = acc + q(addmat?) + q(addmat2); updates cstate
//            fp32, writes hout bf16;
//        4 = bf16 q-layout store (within each 64-col group, gate innermost:
//            qcol = group + lr*4 + n) via one ushort4 store per (m,r2).
// AMODE: 0 = none; 1 = fp32 addmat[row*N+col]; 3 = fp32 addmat[gate_perm(row)*N+col];
//        5 = bf16 q-layout addmat (ushort4 at row*N + group + lr*4).
template<int SMODE, int AMODE>
__global__ __launch_bounds__(256, 2)
void gemm_bt(const unsigned short* __restrict__ A1, long lda1,
             const unsigned short* __restrict__ A2, long lda2, int K1,
             const unsigned short* __restrict__ W1, const unsigned short* __restrict__ W2,
             int N, int K,
             const float* __restrict__ bias,
             const void* __restrict__ addmat, const void* __restrict__ addmat2,
             void* __restrict__ outp, long ldo,
             float* __restrict__ cstate, unsigned short* __restrict__ hout)
{
  __shared__ unsigned short As[128 * 64];
  __shared__ unsigned short Bs[128 * 64];
  const int tid = threadIdx.x, lane = tid & 63, wave = tid >> 6;
  const long bm = blockIdx.x, bn = blockIdx.y;

  f32x4 acc[4][4] = {};

  const int nkt = K >> 6;
  const int wm = wave >> 1, wn = wave & 1;
  const int lr = lane & 15, lq = lane >> 4;

  for (int kt = 0; kt < nkt; ++kt) {
    const int k0 = kt << 6;
    const unsigned short* Ab; long lda; const unsigned short* Wb; long ldw; int ko;
    if (k0 < K1) { Ab = A1; lda = lda1; Wb = W1; ldw = K1;      ko = k0; }
    else         { Ab = A2; lda = lda2; Wb = W2; ldw = K - K1;  ko = k0 - K1; }
    __syncthreads();
    #pragma unroll
    for (int it = 0; it < 4; ++it) {
      const int c0 = it * 256 + wave * 64;
      const int c = c0 + lane;
      const int row = c >> 3, sub = c & 7;
      gload16(Ab + (bm * 128 + row) * lda + ko + sub * 8, &As[c0 * 8]);
      gload16(Wb + (bn * 128 + row) * ldw + ko + sub * 8, &Bs[c0 * 8]);
    }
    __syncthreads();
    #pragma unroll
    for (int kk = 0; kk < 2; ++kk) {
      short8 av[4], bv[4];
      const int lk = kk * 32 + lq * 8;
      #pragma unroll
      for (int m = 0; m < 4; ++m)
        av[m] = *reinterpret_cast<const short8*>(&As[(wm * 64 + m * 16 + lr) * 64 + lk]);
      #pragma unroll
      for (int n = 0; n < 4; ++n)
        bv[n] = *reinterpret_cast<const short8*>(&Bs[(wn * 64 + n * 16 + lr) * 64 + lk]);
      #pragma unroll
      for (int m = 0; m < 4; ++m)
        #pragma unroll
        for (int n = 0; n < 4; ++n)
          acc[m][n] = __builtin_amdgcn_mfma_f32_16x16x32_bf16(av[m], bv[n], acc[m][n], 0, 0, 0);
    }
  }

  const long grp = bn * 128 + wn * 64;

  if constexpr (SMODE == 3) {
    // fused LSTM cell: thread's n=0..3 fragments are i,f,g,o for h = bn*32+wn*16+lr
    const int hcol = (int)bn * 32 + wn * 16 + lr;
    #pragma unroll
    for (int m = 0; m < 4; ++m) {
      #pragma unroll
      for (int r2 = 0; r2 < 4; ++r2) {
        const long row = bm * 128 + wm * 64 + m * 16 + lq * 4 + r2;
        const long qbase = row * (long)N + grp + lr * 4;
        ushort4 tq = *reinterpret_cast<const ushort4*>(
            &((const unsigned short*)addmat2)[qbase]);
        float gi = acc[m][0][r2] + b2f(tq.x);
        float gf = acc[m][1][r2] + b2f(tq.y);
        float gg = acc[m][2][r2] + b2f(tq.z);
        float go = acc[m][3][r2] + b2f(tq.w);
        if (addmat) {
          ushort4 gq = *reinterpret_cast<const ushort4*>(
              &((const unsigned short*)addmat)[qbase]);
          gi += b2f(gq.x); gf += b2f(gq.y); gg += b2f(gq.z); go += b2f(gq.w);
        }
        const long ci = row * HID_ + hcol;
        float c = cstate[ci];
        c = sigmoidf_(gf) * c + sigmoidf_(gi) * tanh_fast(gg);
        cstate[ci] = c;
        hout[ci] = f2b(sigmoidf_(go) * tanh_fast(c));
      }
    }
    return;
  }

  if constexpr (SMODE == 4) {
    // q-layout bf16 store (gate innermost), one ushort4 per (m,r2)
    #pragma unroll
    for (int m = 0; m < 4; ++m) {
      #pragma unroll
      for (int r2 = 0; r2 < 4; ++r2) {
        const long row = bm * 128 + wm * 64 + m * 16 + lq * 4 + r2;
        float v[4];
        #pragma unroll
        for (int n = 0; n < 4; ++n) {
          const long col = grp + n * 16 + lr;
          v[n] = acc[m][n][r2] + (bias ? bias[col] : 0.0f);
        }
        if constexpr (AMODE == 5) {
          ushort4 a4 = *reinterpret_cast<const ushort4*>(
              &((const unsigned short*)addmat)[row * (long)N + grp + lr * 4]);
          v[0] += b2f(a4.x); v[1] += b2f(a4.y); v[2] += b2f(a4.z); v[3] += b2f(a4.w);
        }
        ushort4 o;
        o.x = f2b(v[0]); o.y = f2b(v[1]); o.z = f2b(v[2]); o.w = f2b(v[3]);
        *reinterpret_cast<ushort4*>(
            &reinterpret_cast<unsigned short*>(outp)[row * ldo + grp + lr * 4]) = o;
      }
    }
    return;
  }

  // standard epilogues
  #pragma unroll
  for (int m = 0; m < 4; ++m) {
    #pragma unroll
    for (int n = 0; n < 4; ++n) {
      const long col = grp + n * 16 + lr;
      const float bvv = bias ? bias[col] : 0.0f;
      #pragma unroll
      for (int r2 = 0; r2 < 4; ++r2) {
        const long row = bm * 128 + wm * 64 + m * 16 + lq * 4 + r2;
        float v = acc[m][n][r2] + bvv;
        if constexpr (AMODE == 1) v += ((const float*)addmat)[row * (long)N + col];
        if constexpr (AMODE == 3) v += ((const float*)addmat)[(long)gate_perm((int)row) * N + col];
        if constexpr (SMODE == 0) {
          reinterpret_cast<float*>(outp)[row * ldo + col] = v;
        } else if constexpr (SMODE == 1) {
          reinterpret_cast<unsigned short*>(outp)[row * ldo + col] = f2b(v);
        } else {
          const long bb = row & 1023, tt = (row >> 10) + 1;
          reinterpret_cast<float*>(outp)[bb * (T_ * MAN_) + tt * MAN_ + col] = v;
        }
      }
    }
  }
}

// ---------------- persistent cooperative step kernel: nsteps LSTM steps ----------------
// grid = 512 blocks (8 bm x 64 bn), 2 blocks/CU (gated by occupancy query on host).
// XCD-swizzled so each XCD owns 8 consecutive bn panels of Whh. Inner GEMM is the
// R2-proven single-buffer 2-barrier structure; cell fused in epilogue reads q-layout
// xg + TB (ushort4 each). Explicit agent-scope fences around grid.sync() guarantee
// cross-XCD visibility of h/c stores (Guideline 16) independent of sync internals.
__global__ __launch_bounds__(256, 2)
void steps_persistent(const unsigned short* __restrict__ Whh,
                      const unsigned short* __restrict__ xg,
                      const unsigned short* __restrict__ TBa,
                      const unsigned short* __restrict__ TBb,
                      unsigned short* __restrict__ hstore,
                      float* __restrict__ cstate,
                      int t0, int nsteps)
{
  cg::grid_group gg_ = cg::this_grid();
  __shared__ unsigned short As[128 * 64];
  __shared__ unsigned short Bs[128 * 64];
  const int tid = threadIdx.x, lane = tid & 63, wave = tid >> 6;
  const int flat = (int)blockIdx.x;
  const int sw = (flat & 7) * 64 + (flat >> 3);   // m204 bijective, nwg=512
  const long bm = sw & 7, bn = sw >> 3;           // XCD k owns bn in [8k, 8k+8)
  const int wm = wave >> 1, wn = wave & 1;
  const int lr = lane & 15, lq = lane >> 4;
  const int hcol = (int)bn * 32 + wn * 16 + lr;
  const long grp = bn * 128 + wn * 64;

  for (int s = 0; s < nsteps; ++s) {
    const int t = t0 + s;
    const unsigned short* A = hstore + (long)(t - 1) * B_ * HID_;
    unsigned short* hout    = hstore + (long)t * B_ * HID_;
    const unsigned short* xgs = xg + (long)s * B_ * NG_;
    const unsigned short* TBq = (t == 1) ? TBa : TBb;

    f32x4 acc[4][4] = {};
    for (int kt = 0; kt < HID_ / 64; ++kt) {
      const int ko = kt << 6;
      __syncthreads();
      #pragma unroll
      for (int it = 0; it < 4; ++it) {
        const int c0 = it * 256 + wave * 64;
        const int c = c0 + lane;
        const int row = c >> 3, sub = c & 7;
        gload16(A   + (bm * 128 + row) * HID_ + ko + sub * 8, &As[c0 * 8]);
        gload16(Whh + (bn * 128 + row) * HID_ + ko + sub * 8, &Bs[c0 * 8]);
      }
      __syncthreads();
      #pragma unroll
      for (int kk = 0; kk < 2; ++kk) {
        short8 av[4], bv[4];
        const int lk = kk * 32 + lq * 8;
        #pragma unroll
        for (int m = 0; m < 4; ++m)
          av[m] = *reinterpret_cast<const short8*>(&As[(wm * 64 + m * 16 + lr) * 64 + lk]);
        #pragma unroll
        for (int n = 0; n < 4; ++n)
          bv[n] = *reinterpret_cast<const short8*>(&Bs[(wn * 64 + n * 16 + lr) * 64 + lk]);
        #pragma unroll
        for (int m = 0; m < 4; ++m)
          #pragma unroll
          for (int n = 0; n < 4; ++n)
            acc[m][n] = __builtin_amdgcn_mfma_f32_16x16x32_bf16(av[m], bv[n], acc[m][n], 0, 0, 0);
      }
    }

    // fused LSTM cell: q-layout xg + TB (ushort4 = i,f,g,o)
    #pragma unroll
    for (int m = 0; m < 4; ++m) {
      #pragma unroll
      for (int r2 = 0; r2 < 4; ++r2) {
        const long row = bm * 128 + wm * 64 + m * 16 + lq * 4 + r2;
        const long qbase = row * (long)NG_ + grp + lr * 4;
        ushort4 gq = *reinterpret_cast<const ushort4*>(&xgs[qbase]);
        ushort4 tq = *reinterpret_cast<const ushort4*>(&TBq[qbase]);
        float gi = acc[m][0][r2] + b2f(gq.x) + b2f(tq.x);
        float gf = acc[m][1][r2] + b2f(gq.y) + b2f(tq.y);
        float ggt = acc[m][2][r2] + b2f(gq.z) + b2f(tq.z);
        float go = acc[m][3][r2] + b2f(gq.w) + b2f(tq.w);
        const long ci = row * HID_ + hcol;
        float c = cstate[ci];
        c = sigmoidf_(gf) * c + sigmoidf_(gi) * tanh_fast(ggt);
        cstate[ci] = c;
        hout[ci] = f2b(sigmoidf_(go) * tanh_fast(c));
      }
    }
    __threadfence();   // release: drain + write back L2 (agent scope)
    gg_.sync();
    __threadfence();   // acquire: invalidate L2 so next step reads fresh h
  }
}

// ---------------- launcher ----------------
extern "C" void kernel_launch(void* const* d_in, const int* in_sizes, int n_in,
                              void* d_out, int out_size, void* d_ws, size_t ws_size,
                              hipStream_t stream) {
  const float* input_repr = (const float*)d_in[0];
  const float* time_enc   = (const float*)d_in[1];
  const float* y0         = (const float*)d_in[2];
  const float* W_ih       = (const float*)d_in[3];
  const float* b_ih       = (const float*)d_in[4];
  const float* W_hh       = (const float*)d_in[5];
  const float* b_hh       = (const float*)d_in[6];
  const float* W_mu       = (const float*)d_in[7];
  const float* b_mu       = (const float*)d_in[8];
  float* out = (float*)d_out;

  char* ws = (char*)d_ws;
  auto alloc = [&](size_t bytes) {
    char* p = ws; ws += (bytes + 255) & ~(size_t)255; return p;
  };
  unsigned short* Xtm    = (unsigned short*)alloc((size_t)T_ * B_ * FEAT_ * 2);   // 134 MB (time-major)
  unsigned short* hstore = (unsigned short*)alloc((size_t)T_ * B_ * HID_ * 2);    // 268 MB
  float*  cst   = (float*)alloc((size_t)B_ * HID_ * 4);                           // 8.4 MB
  unsigned short* TB2 = (unsigned short*)alloc((size_t)B_ * NG_ * 2);             // 16.8 MB (bf16, q-layout)
  unsigned short* TB1 = (unsigned short*)alloc((size_t)B_ * NG_ * 2);             // 16.8 MB (q-layout)
  unsigned short* Whhf  = (unsigned short*)alloc((size_t)NG_ * HID_ * 2);         // 33.5 MB (perm rows)
  unsigned short* Wxbf  = (unsigned short*)alloc((size_t)NG_ * FEAT_ * 2);        // 16.8 MB (perm rows)
  unsigned short* Wybf  = (unsigned short*)alloc((size_t)NG_ * MAN_ * 2);         // (perm rows)
  unsigned short* Wtebf = (unsigned short*)alloc((size_t)NG_ * TENC_ * 2);        // (perm rows)
  unsigned short* WmuT  = (unsigned short*)alloc((size_t)HID_ * MAN_ * 2);
  unsigned short* Wmubf = (unsigned short*)alloc((size_t)MAN_ * HID_ * 2);
  unsigned short* tebf  = (unsigned short*)alloc((size_t)B_ * TENC_ * 2);
  unsigned short* y0bf  = (unsigned short*)alloc((size_t)B_ * MAN_ * 2);
  float* bvec2 = (float*)alloc(NG_ * 4);
  float* nbm   = (float*)alloc(NG_ * 4);
  size_t base_bytes = (size_t)(ws - (char*)d_ws);
  // xg chunk buffer: CHUNK_ slabs of B_*NG_ bf16 (352 MB), q-layout, pure x@Wx
  size_t xg_bytes = (size_t)CHUNK_ * B_ * NG_ * 2;
  bool use_xg = (base_bytes + xg_bytes + 4096) <= ws_size;
  unsigned short* xg = use_xg ? (unsigned short*)alloc(xg_bytes) : nullptr;

  // cooperative-launch feasibility gate (capture-safe query, deterministic)
  int maxb = 0;
  bool coop_ok = use_xg &&
      (hipOccupancyMaxActiveBlocksPerMultiprocessor(&maxb, steps_persistent, 256, 0)
           == hipSuccess) && (maxb >= 2);

  // --- conversions / preps (all parallel work) ---
  pack_x_tm<<<B_ * T_, 256, 0, stream>>>(input_repr, Xtm);
  pack_wih<<<dim3(2, NG_), 256, 0, stream>>>(W_ih, Wxbf, Wybf, Wtebf);
  pack_bf16<<<dim3(2, MAN_), 256, 0, stream>>>(W_mu, HID_, 0, Wmubf, HID_);
  pack_bf16<<<dim3(1, B_), 256, 0, stream>>>(time_enc, TENC_, 0, tebf, TENC_);
  pack_bf16<<<dim3(1, B_), 256, 0, stream>>>(y0, MAN_, 0, y0bf, MAN_);
  transpose_to_bf16<<<1024, 256, 0, stream>>>(W_mu, WmuT);
  bias_prep<<<NG_ / 256, 256, 0, stream>>>(W_ih, b_ih, b_hh, b_mu, bvec2, nbm);
  zero_u32<<<(B_ * HID_ / 2 + 255) / 256, 256, 0, stream>>>((unsigned int*)hstore, (long)B_ * HID_ / 2); // h0 = 0
  zero_u32<<<(B_ * HID_ + 255) / 256, 256, 0, stream>>>((unsigned int*)cst, (long)B_ * HID_);            // c0 = 0
  out_t0<<<B_ * MAN_ / 256, 256, 0, stream>>>(y0, out);

  // Whhf = perm(W_hh) + permWy @ W_mu   (bf16, rows permuted)   M=NG_, N=HID_, K=MAN_
  gemm_bt<1, 3><<<dim3(NG_ / 128, HID_ / 128), 256, 0, stream>>>(
      Wybf, MAN_, Wybf, MAN_, MAN_, WmuT, WmuT, HID_, MAN_,
      nullptr, W_hh, nullptr, Whhf, HID_, nullptr, nullptr);
  // TB2 = q(te @ permWte^T + bvec2)                M=B_, N=NG_, K=TENC_ (bf16 q-layout)
  gemm_bt<4, 0><<<dim3(B_ / 128, NG_ / 128), 256, 0, stream>>>(
      tebf, TENC_, tebf, TENC_, TENC_, Wtebf, Wtebf, NG_, TENC_,
      bvec2, nullptr, nullptr, TB2, NG_, nullptr, nullptr);
  // TB1 = q(y0 @ permWy^T + nbm) + TB2(q)          M=B_, N=NG_, K=MAN_ (bf16 q-layout)
  gemm_bt<4, 5><<<dim3(B_ / 128, NG_ / 128), 256, 0, stream>>>(
      y0bf, MAN_, y0bf, MAN_, MAN_, Wybf, Wybf, NG_, MAN_,
      nbm, TB2, nullptr, TB1, NG_, nullptr, nullptr);

  if (use_xg) {
    // --- recurrence in 3 chunks: xg = x@permWx^T only (q-layout, no TB read),
    //     then 21 steps: persistent cooperative if possible, else per-step ---
    for (int c = 0; c < 3; ++c) {
      int t0 = 1 + c * CHUNK_;
      int ns = CHUNK_;
      gemm_bt<4, 0><<<dim3(CHUNK_ * B_ / 128, NG_ / 128), 256, 0, stream>>>(
          Xtm + (long)t0 * B_ * FEAT_, FEAT_, Xtm, FEAT_, 1024,
          Wxbf, Wxbf, NG_, 1024,
          nullptr, nullptr, nullptr, xg, NG_, nullptr, nullptr);
      if (coop_ok) {
        const unsigned short* Whh_c = Whhf;
        const unsigned short* xg_c = xg;
        const unsigned short* tb1_c = TB1;
        const unsigned short* tb2_c = TB2;
        unsigned short* hs_c = hstore;
        float* cst_c = cst;
        void* kargs[] = {(void*)&Whh_c, (void*)&xg_c, (void*)&tb1_c, (void*)&tb2_c,
                         (void*)&hs_c, (void*)&cst_c, (void*)&t0, (void*)&ns};
        if (hipLaunchCooperativeKernel((const void*)steps_persistent,
                                       dim3(512), dim3(256), kargs, 0, stream)
            != hipSuccess)
          coop_ok = false;   // fall through to per-step for this and later chunks
      }
      if (!coop_ok) {
        for (int t = t0; t < t0 + CHUNK_; ++t) {
          const unsigned short* A2 = hstore + (long)(t - 1) * B_ * HID_;
          gemm_bt<3, 0><<<dim3(B_ / 128, NG_ / 128), 256, 0, stream>>>(
              A2, HID_, A2, HID_, HID_,
              Whhf, Whhf, NG_, HID_,
              nullptr, xg + (long)(t - t0) * B_ * NG_, (t == 1 ? TB1 : TB2), nullptr, 0,
              cst, hstore + (long)t * B_ * HID_);
        }
      }
    }
  } else {
    // fallback: per-step K=3072 two-region GEMM + fused cell (TB via q-addmat2)
    for (int t = 1; t < T_; ++t) {
      const unsigned short* A1 = Xtm + (long)t * B_ * FEAT_;
      const unsigned short* A2 = hstore + (long)(t - 1) * B_ * HID_;
      gemm_bt<3, 0><<<dim3(B_ / 128, NG_ / 128), 256, 0, stream>>>(
          A1, FEAT_, A2, HID_, FEAT_,
          Wxbf, Whhf, NG_, FEAT_ + HID_,
          nullptr, nullptr, (t == 1 ? TB1 : TB2), nullptr, 0,
          cst, hstore + (long)t * B_ * HID_);
    }
  }

  // --- all outputs y_t = h_t @ W_mu^T + b_mu in one GEMM, scattered into (B,T,MAN) ---
  gemm_bt<2, 0><<<dim3((T_ - 1) * B_ / 128, MAN_ / 128), 256, 0, stream>>>(
      hstore + (long)B_ * HID_, HID_, hstore + (long)B_ * HID_, HID_, HID_,
      Wmubf, Wmubf, MAN_, HID_,
      b_mu, nullptr, nullptr, out, 0, nullptr, nullptr);
}

// Round 7
// 5496.129 us; speedup vs baseline: 1.0322x; 1.0322x over previous
//
#include <hip/hip_runtime.h>
#include <hip/hip_bf16.h>

#define B_ 1024
#define T_ 64
#define FEAT_ 1024
#define TENC_ 256
#define MAN_ 128
#define HID_ 2048
#define NG_ 8192   /* 4*HID */
#define IND_ 1408
#define CHUNK_ 21  /* 63 = 3 * 21 steps of xg precompute */

typedef __attribute__((ext_vector_type(8))) short short8;
typedef __attribute__((ext_vector_type(4))) float f32x4;

typedef const __attribute__((address_space(1))) void as1_cvoid;
typedef __attribute__((address_space(3))) void as3_void;

static __device__ __forceinline__ float sigmoidf_(float x) {
  return 1.0f / (1.0f + __expf(-x));
}
static __device__ __forceinline__ float tanh_fast(float x) {
  return 1.0f - 2.0f / (__expf(2.0f * x) + 1.0f);
}
static __device__ __forceinline__ unsigned short f2b(float x) {
  __hip_bfloat16 h = __float2bfloat16(x);
  return *reinterpret_cast<unsigned short*>(&h);
}
static __device__ __forceinline__ float b2f(unsigned short u) {
  unsigned int v = ((unsigned int)u) << 16;
  return *reinterpret_cast<float*>(&v);
}

// gate permutation: new col p -> original gate-matrix row
// gate = (p>>4)&3, h = (p>>7)*32 + ((p>>6)&1)*16 + (p&15)
static __device__ __forceinline__ int gate_perm(int p) {
  int h = ((p >> 7) << 5) + (((p >> 6) & 1) << 4) + (p & 15);
  int gate = (p >> 4) & 3;
  return gate * HID_ + h;
}

__device__ __forceinline__ void gload16(const unsigned short* g, unsigned short* l) {
  __builtin_amdgcn_global_load_lds((as1_cvoid*)g, (as3_void*)l, 16, 0, 0);
}

// ---------------- small prep kernels ----------------

__global__ void zero_u32(unsigned int* p, long n) {
  long i = (long)blockIdx.x * blockDim.x + threadIdx.x;
  if (i < n) p[i] = 0u;
}

// X [b][t][f] fp32 -> Xtm [t][b][f] bf16
__global__ void pack_x_tm(const float* __restrict__ src, unsigned short* __restrict__ dst) {
  int c = threadIdx.x * 4;
  int bt = blockIdx.x;
  int b = bt >> 6, t = bt & 63;
  float4 v = *reinterpret_cast<const float4*>(&src[((long)b * T_ + t) * FEAT_ + c]);
  ushort4 o;
  o.x = f2b(v.x); o.y = f2b(v.y); o.z = f2b(v.z); o.w = f2b(v.w);
  *reinterpret_cast<ushort4*>(&dst[((long)t * B_ + b) * FEAT_ + c]) = o;
}

// fp32 (rows x cols slice) -> contiguous bf16
__global__ void pack_bf16(const float* __restrict__ src, long ld, long off,
                          unsigned short* __restrict__ dst, long cols) {
  long c = ((long)blockIdx.x * blockDim.x + threadIdx.x) * 4;
  if (c >= cols) return;
  long r = blockIdx.y;
  float4 v = *reinterpret_cast<const float4*>(&src[r * ld + off + c]);
  ushort4 o;
  o.x = f2b(v.x); o.y = f2b(v.y); o.z = f2b(v.z); o.w = f2b(v.w);
  *reinterpret_cast<ushort4*>(&dst[r * cols + c]) = o;
}

// one-pass W_ih split: row rd (gate-permuted from src), cols -> Wx | Wy | Wte (bf16)
__global__ void pack_wih(const float* __restrict__ W_ih,
                         unsigned short* __restrict__ Wx,
                         unsigned short* __restrict__ Wy,
                         unsigned short* __restrict__ Wte) {
  int c = (blockIdx.x * 256 + threadIdx.x) * 4;
  if (c >= IND_) return;
  long rd = blockIdx.y;
  long rs = gate_perm((int)rd);
  float4 v = *reinterpret_cast<const float4*>(&W_ih[rs * IND_ + c]);
  ushort4 o;
  o.x = f2b(v.x); o.y = f2b(v.y); o.z = f2b(v.z); o.w = f2b(v.w);
  if (c < FEAT_) {
    *reinterpret_cast<ushort4*>(&Wx[rd * FEAT_ + c]) = o;
  } else if (c < FEAT_ + MAN_) {
    *reinterpret_cast<ushort4*>(&Wy[rd * MAN_ + (c - FEAT_)]) = o;
  } else {
    *reinterpret_cast<ushort4*>(&Wte[rd * TENC_ + (c - FEAT_ - MAN_)]) = o;
  }
}

// WmuT[n][m] = bf16(W_mu[m][n]);  W_mu: (MAN_, HID_)
__global__ void transpose_to_bf16(const float* __restrict__ src, unsigned short* __restrict__ dst) {
  int i = blockIdx.x * 256 + threadIdx.x;       // over HID_*MAN_
  int n = i >> 7, m = i & 127;
  dst[i] = f2b(src[(long)m * HID_ + n]);
}

// permuted: bvec2[p] = (b_ih + b_hh + b_mu@Wy^T)[gate_perm(p)];  nbm[p] = -(b_mu@Wy^T)[gate_perm(p)]
__global__ void bias_prep(const float* __restrict__ W_ih, const float* __restrict__ b_ih,
                          const float* __restrict__ b_hh, const float* __restrict__ b_mu,
                          float* __restrict__ bvec2, float* __restrict__ nbm) {
  int p = blockIdx.x * 256 + threadIdx.x;
  if (p >= NG_) return;
  int g = gate_perm(p);
  const float* wy = &W_ih[(long)g * IND_ + FEAT_];
  float s = 0.f;
  #pragma unroll 8
  for (int m = 0; m < MAN_; ++m) s += b_mu[m] * wy[m];
  bvec2[p] = b_ih[g] + b_hh[g] + s;
  nbm[p] = -s;
}

__global__ void out_t0(const float* __restrict__ y0, float* __restrict__ out) {
  int i = blockIdx.x * 256 + threadIdx.x;       // over B_*MAN_
  int b = i >> 7, m = i & 127;
  out[(long)b * (T_ * MAN_) + m] = y0[i];
}

// ---------------- generic bf16 MFMA GEMM: C = A @ W^T (+bias[col]) (+addmat) ----------
// A: M x K via two K-regions (boundary K1). W: N x K via two regions, bf16 row-major.
// R2-proven structure: single LDS buffer, two barriers per K-tile.
// SWZ (step launches only, grid MUST be 8 x 64): remap blocks so XCD k owns
// bn in [8k, 8k+8) -> per-XCD Whh slice = 4.19 MB, L2-resident ACROSS the 63
// per-step launches (no flush between kernels, deterministic dispatch).
// SMODE: 0 = fp32 store at out[row*ldo+col]; 1 = bf16 store; 2 = decoder scatter
//        (row -> b=row&1023, t=(row>>10)+1; out[b*T*MAN + t*MAN + col], fp32);
//        3 = fused LSTM cell: gates = acc + q(addmat?) + q(addmat2); updates cstate
//            fp32, writes hout bf16;
//        4 = bf16 q-layout store (within each 64-col group, gate innermost:
//            qcol = group + lr*4 + n) via one ushort4 store per (m,r2).
// AMODE: 0 = none; 1 = fp32 addmat[row*N+col]; 3 = fp32 addmat[gate_perm(row)*N+col];
//        5 = bf16 q-layout addmat (ushort4 at row*N + group + lr*4).
template<int SMODE, int AMODE, bool SWZ = false>
__global__ __launch_bounds__(256, 2)
void gemm_bt(const unsigned short* __restrict__ A1, long lda1,
             const unsigned short* __restrict__ A2, long lda2, int K1,
             const unsigned short* __restrict__ W1, const unsigned short* __restrict__ W2,
             int N, int K,
             const float* __restrict__ bias,
             const void* __restrict__ addmat, const void* __restrict__ addmat2,
             void* __restrict__ outp, long ldo,
             float* __restrict__ cstate, unsigned short* __restrict__ hout)
{
  __shared__ unsigned short As[128 * 64];
  __shared__ unsigned short Bs[128 * 64];
  const int tid = threadIdx.x, lane = tid & 63, wave = tid >> 6;

  long bm, bn;
  if constexpr (SWZ) {
    // grid 8x64, flat%8 == XCD (round-robin dispatch): XCD k gets bn in [8k,8k+8)
    const int f = (int)(blockIdx.y * gridDim.x + blockIdx.x);
    const int j = f >> 3;
    bm = j >> 3;
    bn = (long)(f & 7) * 8 + (j & 7);
  } else {
    bm = blockIdx.x; bn = blockIdx.y;
  }

  f32x4 acc[4][4] = {};

  const int nkt = K >> 6;
  const int wm = wave >> 1, wn = wave & 1;
  const int lr = lane & 15, lq = lane >> 4;

  for (int kt = 0; kt < nkt; ++kt) {
    const int k0 = kt << 6;
    const unsigned short* Ab; long lda; const unsigned short* Wb; long ldw; int ko;
    if (k0 < K1) { Ab = A1; lda = lda1; Wb = W1; ldw = K1;      ko = k0; }
    else         { Ab = A2; lda = lda2; Wb = W2; ldw = K - K1;  ko = k0 - K1; }
    __syncthreads();
    #pragma unroll
    for (int it = 0; it < 4; ++it) {
      const int c0 = it * 256 + wave * 64;
      const int c = c0 + lane;
      const int row = c >> 3, sub = c & 7;
      gload16(Ab + (bm * 128 + row) * lda + ko + sub * 8, &As[c0 * 8]);
      gload16(Wb + (bn * 128 + row) * ldw + ko + sub * 8, &Bs[c0 * 8]);
    }
    __syncthreads();
    #pragma unroll
    for (int kk = 0; kk < 2; ++kk) {
      short8 av[4], bv[4];
      const int lk = kk * 32 + lq * 8;
      #pragma unroll
      for (int m = 0; m < 4; ++m)
        av[m] = *reinterpret_cast<const short8*>(&As[(wm * 64 + m * 16 + lr) * 64 + lk]);
      #pragma unroll
      for (int n = 0; n < 4; ++n)
        bv[n] = *reinterpret_cast<const short8*>(&Bs[(wn * 64 + n * 16 + lr) * 64 + lk]);
      #pragma unroll
      for (int m = 0; m < 4; ++m)
        #pragma unroll
        for (int n = 0; n < 4; ++n)
          acc[m][n] = __builtin_amdgcn_mfma_f32_16x16x32_bf16(av[m], bv[n], acc[m][n], 0, 0, 0);
    }
  }

  const long grp = bn * 128 + wn * 64;

  if constexpr (SMODE == 3) {
    // fused LSTM cell: thread's n=0..3 fragments are i,f,g,o for h = bn*32+wn*16+lr
    const int hcol = (int)bn * 32 + wn * 16 + lr;
    #pragma unroll
    for (int m = 0; m < 4; ++m) {
      #pragma unroll
      for (int r2 = 0; r2 < 4; ++r2) {
        const long row = bm * 128 + wm * 64 + m * 16 + lq * 4 + r2;
        const long qbase = row * (long)N + grp + lr * 4;
        ushort4 tq = *reinterpret_cast<const ushort4*>(
            &((const unsigned short*)addmat2)[qbase]);
        float gi = acc[m][0][r2] + b2f(tq.x);
        float gf = acc[m][1][r2] + b2f(tq.y);
        float gg = acc[m][2][r2] + b2f(tq.z);
        float go = acc[m][3][r2] + b2f(tq.w);
        if (addmat) {
          ushort4 gq = *reinterpret_cast<const ushort4*>(
              &((const unsigned short*)addmat)[qbase]);
          gi += b2f(gq.x); gf += b2f(gq.y); gg += b2f(gq.z); go += b2f(gq.w);
        }
        const long ci = row * HID_ + hcol;
        float c = cstate[ci];
        c = sigmoidf_(gf) * c + sigmoidf_(gi) * tanh_fast(gg);
        cstate[ci] = c;
        hout[ci] = f2b(sigmoidf_(go) * tanh_fast(c));
      }
    }
    return;
  }

  if constexpr (SMODE == 4) {
    // q-layout bf16 store (gate innermost), one ushort4 per (m,r2)
    #pragma unroll
    for (int m = 0; m < 4; ++m) {
      #pragma unroll
      for (int r2 = 0; r2 < 4; ++r2) {
        const long row = bm * 128 + wm * 64 + m * 16 + lq * 4 + r2;
        float v[4];
        #pragma unroll
        for (int n = 0; n < 4; ++n) {
          const long col = grp + n * 16 + lr;
          v[n] = acc[m][n][r2] + (bias ? bias[col] : 0.0f);
        }
        if constexpr (AMODE == 5) {
          ushort4 a4 = *reinterpret_cast<const ushort4*>(
              &((const unsigned short*)addmat)[row * (long)N + grp + lr * 4]);
          v[0] += b2f(a4.x); v[1] += b2f(a4.y); v[2] += b2f(a4.z); v[3] += b2f(a4.w);
        }
        ushort4 o;
        o.x = f2b(v[0]); o.y = f2b(v[1]); o.z = f2b(v[2]); o.w = f2b(v[3]);
        *reinterpret_cast<ushort4*>(
            &reinterpret_cast<unsigned short*>(outp)[row * ldo + grp + lr * 4]) = o;
      }
    }
    return;
  }

  // standard epilogues
  #pragma unroll
  for (int m = 0; m < 4; ++m) {
    #pragma unroll
    for (int n = 0; n < 4; ++n) {
      const long col = grp + n * 16 + lr;
      const float bvv = bias ? bias[col] : 0.0f;
      #pragma unroll
      for (int r2 = 0; r2 < 4; ++r2) {
        const long row = bm * 128 + wm * 64 + m * 16 + lq * 4 + r2;
        float v = acc[m][n][r2] + bvv;
        if constexpr (AMODE == 1) v += ((const float*)addmat)[row * (long)N + col];
        if constexpr (AMODE == 3) v += ((const float*)addmat)[(long)gate_perm((int)row) * N + col];
        if constexpr (SMODE == 0) {
          reinterpret_cast<float*>(outp)[row * ldo + col] = v;
        } else if constexpr (SMODE == 1) {
          reinterpret_cast<unsigned short*>(outp)[row * ldo + col] = f2b(v);
        } else {
          const long bb = row & 1023, tt = (row >> 10) + 1;
          reinterpret_cast<float*>(outp)[bb * (T_ * MAN_) + tt * MAN_ + col] = v;
        }
      }
    }
  }
}

// ---------------- launcher ----------------
extern "C" void kernel_launch(void* const* d_in, const int* in_sizes, int n_in,
                              void* d_out, int out_size, void* d_ws, size_t ws_size,
                              hipStream_t stream) {
  const float* input_repr = (const float*)d_in[0];
  const float* time_enc   = (const float*)d_in[1];
  const float* y0         = (const float*)d_in[2];
  const float* W_ih       = (const float*)d_in[3];
  const float* b_ih       = (const float*)d_in[4];
  const float* W_hh       = (const float*)d_in[5];
  const float* b_hh       = (const float*)d_in[6];
  const float* W_mu       = (const float*)d_in[7];
  const float* b_mu       = (const float*)d_in[8];
  float* out = (float*)d_out;

  char* ws = (char*)d_ws;
  auto alloc = [&](size_t bytes) {
    char* p = ws; ws += (bytes + 255) & ~(size_t)255; return p;
  };
  unsigned short* Xtm    = (unsigned short*)alloc((size_t)T_ * B_ * FEAT_ * 2);   // 134 MB (time-major)
  unsigned short* hstore = (unsigned short*)alloc((size_t)T_ * B_ * HID_ * 2);    // 268 MB
  float*  cst   = (float*)alloc((size_t)B_ * HID_ * 4);                           // 8.4 MB
  unsigned short* TB2 = (unsigned short*)alloc((size_t)B_ * NG_ * 2);             // 16.8 MB (bf16, q-layout)
  unsigned short* TB1 = (unsigned short*)alloc((size_t)B_ * NG_ * 2);             // 16.8 MB (q-layout)
  unsigned short* Whhf  = (unsigned short*)alloc((size_t)NG_ * HID_ * 2);         // 33.5 MB (perm rows)
  unsigned short* Wxbf  = (unsigned short*)alloc((size_t)NG_ * FEAT_ * 2);        // 16.8 MB (perm rows)
  unsigned short* Wybf  = (unsigned short*)alloc((size_t)NG_ * MAN_ * 2);         // (perm rows)
  unsigned short* Wtebf = (unsigned short*)alloc((size_t)NG_ * TENC_ * 2);        // (perm rows)
  unsigned short* WmuT  = (unsigned short*)alloc((size_t)HID_ * MAN_ * 2);
  unsigned short* Wmubf = (unsigned short*)alloc((size_t)MAN_ * HID_ * 2);
  unsigned short* tebf  = (unsigned short*)alloc((size_t)B_ * TENC_ * 2);
  unsigned short* y0bf  = (unsigned short*)alloc((size_t)B_ * MAN_ * 2);
  float* bvec2 = (float*)alloc(NG_ * 4);
  float* nbm   = (float*)alloc(NG_ * 4);
  size_t base_bytes = (size_t)(ws - (char*)d_ws);
  // xg chunk buffer: CHUNK_ slabs of B_*NG_ bf16 (352 MB), q-layout, pure x@Wx
  size_t xg_bytes = (size_t)CHUNK_ * B_ * NG_ * 2;
  bool use_xg = (base_bytes + xg_bytes + 4096) <= ws_size;
  unsigned short* xg = use_xg ? (unsigned short*)alloc(xg_bytes) : nullptr;

  // --- conversions / preps (all parallel work) ---
  pack_x_tm<<<B_ * T_, 256, 0, stream>>>(input_repr, Xtm);
  pack_wih<<<dim3(2, NG_), 256, 0, stream>>>(W_ih, Wxbf, Wybf, Wtebf);
  pack_bf16<<<dim3(2, MAN_), 256, 0, stream>>>(W_mu, HID_, 0, Wmubf, HID_);
  pack_bf16<<<dim3(1, B_), 256, 0, stream>>>(time_enc, TENC_, 0, tebf, TENC_);
  pack_bf16<<<dim3(1, B_), 256, 0, stream>>>(y0, MAN_, 0, y0bf, MAN_);
  transpose_to_bf16<<<1024, 256, 0, stream>>>(W_mu, WmuT);
  bias_prep<<<NG_ / 256, 256, 0, stream>>>(W_ih, b_ih, b_hh, b_mu, bvec2, nbm);
  zero_u32<<<(B_ * HID_ / 2 + 255) / 256, 256, 0, stream>>>((unsigned int*)hstore, (long)B_ * HID_ / 2); // h0 = 0
  zero_u32<<<(B_ * HID_ + 255) / 256, 256, 0, stream>>>((unsigned int*)cst, (long)B_ * HID_);            // c0 = 0
  out_t0<<<B_ * MAN_ / 256, 256, 0, stream>>>(y0, out);

  // Whhf = perm(W_hh) + permWy @ W_mu   (bf16, rows permuted)   M=NG_, N=HID_, K=MAN_
  gemm_bt<1, 3><<<dim3(NG_ / 128, HID_ / 128), 256, 0, stream>>>(
      Wybf, MAN_, Wybf, MAN_, MAN_, WmuT, WmuT, HID_, MAN_,
      nullptr, W_hh, nullptr, Whhf, HID_, nullptr, nullptr);
  // TB2 = q(te @ permWte^T + bvec2)                M=B_, N=NG_, K=TENC_ (bf16 q-layout)
  gemm_bt<4, 0><<<dim3(B_ / 128, NG_ / 128), 256, 0, stream>>>(
      tebf, TENC_, tebf, TENC_, TENC_, Wtebf, Wtebf, NG_, TENC_,
      bvec2, nullptr, nullptr, TB2, NG_, nullptr, nullptr);
  // TB1 = q(y0 @ permWy^T + nbm) + TB2(q)          M=B_, N=NG_, K=MAN_ (bf16 q-layout)
  gemm_bt<4, 5><<<dim3(B_ / 128, NG_ / 128), 256, 0, stream>>>(
      y0bf, MAN_, y0bf, MAN_, MAN_, Wybf, Wybf, NG_, MAN_,
      nbm, TB2, nullptr, TB1, NG_, nullptr, nullptr);

  if (use_xg) {
    // --- recurrence in 3 chunks: xg = x@permWx^T only (q-layout, no TB read),
    //     then 21 per-step fused launches (SWZ: Whh slice L2-resident per XCD) ---
    for (int c = 0; c < 3; ++c) {
      const int t0 = 1 + c * CHUNK_;
      gemm_bt<4, 0><<<dim3(CHUNK_ * B_ / 128, NG_ / 128), 256, 0, stream>>>(
          Xtm + (long)t0 * B_ * FEAT_, FEAT_, Xtm, FEAT_, 1024,
          Wxbf, Wxbf, NG_, 1024,
          nullptr, nullptr, nullptr, xg, NG_, nullptr, nullptr);
      for (int t = t0; t < t0 + CHUNK_; ++t) {
        const unsigned short* A2 = hstore + (long)(t - 1) * B_ * HID_;
        gemm_bt<3, 0, true><<<dim3(B_ / 128, NG_ / 128), 256, 0, stream>>>(
            A2, HID_, A2, HID_, HID_,
            Whhf, Whhf, NG_, HID_,
            nullptr, xg + (long)(t - t0) * B_ * NG_, (t == 1 ? TB1 : TB2), nullptr, 0,
            cst, hstore + (long)t * B_ * HID_);
      }
    }
  } else {
    // fallback: per-step K=3072 two-region GEMM + fused cell (TB via q-addmat2)
    for (int t = 1; t < T_; ++t) {
      const unsigned short* A1 = Xtm + (long)t * B_ * FEAT_;
      const unsigned short* A2 = hstore + (long)(t - 1) * B_ * HID_;
      gemm_bt<3, 0, true><<<dim3(B_ / 128, NG_ / 128), 256, 0, stream>>>(
          A1, FEAT_, A2, HID_, FEAT_,
          Wxbf, Whhf, NG_, FEAT_ + HID_,
          nullptr, nullptr, (t == 1 ? TB1 : TB2), nullptr, 0,
          cst, hstore + (long)t * B_ * HID_);
    }
  }

  // --- all outputs y_t = h_t @ W_mu^T + b_mu in one GEMM, scattered into (B,T,MAN) ---
  gemm_bt<2, 0><<<dim3((T_ - 1) * B_ / 128, MAN_ / 128), 256, 0, stream>>>(
      hstore + (long)B_ * HID_, HID_, hstore + (long)B_ * HID_, HID_, HID_,
      Wmubf, Wmubf, MAN_, HID_,
      b_mu, nullptr, nullptr, out, 0, nullptr, nullptr);
}

// Round 8
// 4364.667 us; speedup vs baseline: 1.2998x; 1.2592x over previous
//
#include <hip/hip_runtime.h>
#include <hip/hip_bf16.h>

#define B_ 1024
#define T_ 64
#define FEAT_ 1024
#define TENC_ 256
#define MAN_ 128
#define HID_ 2048
#define NG_ 8192   /* 4*HID */
#define IND_ 1408

typedef __attribute__((ext_vector_type(8))) short short8;
typedef __attribute__((ext_vector_type(4))) float f32x4;

typedef const __attribute__((address_space(1))) void as1_cvoid;
typedef __attribute__((address_space(3))) void as3_void;

static __device__ __forceinline__ float sigmoidf_(float x) {
  return 1.0f / (1.0f + __expf(-x));
}
static __device__ __forceinline__ float tanh_fast(float x) {
  return 1.0f - 2.0f / (__expf(2.0f * x) + 1.0f);
}
static __device__ __forceinline__ unsigned short f2b(float x) {
  __hip_bfloat16 h = __float2bfloat16(x);
  return *reinterpret_cast<unsigned short*>(&h);
}
static __device__ __forceinline__ float b2f(unsigned short u) {
  unsigned int v = ((unsigned int)u) << 16;
  return *reinterpret_cast<float*>(&v);
}

// gate permutation: new col p -> original gate-matrix row
// gate = (p>>4)&3, h = (p>>7)*32 + ((p>>6)&1)*16 + (p&15)
static __device__ __forceinline__ int gate_perm(int p) {
  int h = ((p >> 7) << 5) + (((p >> 6) & 1) << 4) + (p & 15);
  int gate = (p >> 4) & 3;
  return gate * HID_ + h;
}

__device__ __forceinline__ void gload16(const unsigned short* g, unsigned short* l) {
  __builtin_amdgcn_global_load_lds((as1_cvoid*)g, (as3_void*)l, 16, 0, 0);
}

// ---------------- small prep kernels ----------------

__global__ void zero_u32(unsigned int* p, long n) {
  long i = (long)blockIdx.x * blockDim.x + threadIdx.x;
  if (i < n) p[i] = 0u;
}

// X [b][t][f] fp32 -> Xtm [t][b][f] bf16
__global__ void pack_x_tm(const float* __restrict__ src, unsigned short* __restrict__ dst) {
  int c = threadIdx.x * 4;
  int bt = blockIdx.x;
  int b = bt >> 6, t = bt & 63;
  float4 v = *reinterpret_cast<const float4*>(&src[((long)b * T_ + t) * FEAT_ + c]);
  ushort4 o;
  o.x = f2b(v.x); o.y = f2b(v.y); o.z = f2b(v.z); o.w = f2b(v.w);
  *reinterpret_cast<ushort4*>(&dst[((long)t * B_ + b) * FEAT_ + c]) = o;
}

// fp32 (rows x cols slice) -> contiguous bf16
__global__ void pack_bf16(const float* __restrict__ src, long ld, long off,
                          unsigned short* __restrict__ dst, long cols) {
  long c = ((long)blockIdx.x * blockDim.x + threadIdx.x) * 4;
  if (c >= cols) return;
  long r = blockIdx.y;
  float4 v = *reinterpret_cast<const float4*>(&src[r * ld + off + c]);
  ushort4 o;
  o.x = f2b(v.x); o.y = f2b(v.y); o.z = f2b(v.z); o.w = f2b(v.w);
  *reinterpret_cast<ushort4*>(&dst[r * cols + c]) = o;
}

// one-pass W_ih split: row rd (gate-permuted from src), cols -> Wx | Wy | Wte (bf16)
__global__ void pack_wih(const float* __restrict__ W_ih,
                         unsigned short* __restrict__ Wx,
                         unsigned short* __restrict__ Wy,
                         unsigned short* __restrict__ Wte) {
  int c = (blockIdx.x * 256 + threadIdx.x) * 4;
  if (c >= IND_) return;
  long rd = blockIdx.y;
  long rs = gate_perm((int)rd);
  float4 v = *reinterpret_cast<const float4*>(&W_ih[rs * IND_ + c]);
  ushort4 o;
  o.x = f2b(v.x); o.y = f2b(v.y); o.z = f2b(v.z); o.w = f2b(v.w);
  if (c < FEAT_) {
    *reinterpret_cast<ushort4*>(&Wx[rd * FEAT_ + c]) = o;
  } else if (c < FEAT_ + MAN_) {
    *reinterpret_cast<ushort4*>(&Wy[rd * MAN_ + (c - FEAT_)]) = o;
  } else {
    *reinterpret_cast<ushort4*>(&Wte[rd * TENC_ + (c - FEAT_ - MAN_)]) = o;
  }
}

// WmuT[n][m] = bf16(W_mu[m][n]);  W_mu: (MAN_, HID_)
__global__ void transpose_to_bf16(const float* __restrict__ src, unsigned short* __restrict__ dst) {
  int i = blockIdx.x * 256 + threadIdx.x;       // over HID_*MAN_
  int n = i >> 7, m = i & 127;
  dst[i] = f2b(src[(long)m * HID_ + n]);
}

// permuted: bvec2[p] = (b_ih + b_hh + b_mu@Wy^T)[gate_perm(p)];  nbm[p] = -(b_mu@Wy^T)[gate_perm(p)]
__global__ void bias_prep(const float* __restrict__ W_ih, const float* __restrict__ b_ih,
                          const float* __restrict__ b_hh, const float* __restrict__ b_mu,
                          float* __restrict__ bvec2, float* __restrict__ nbm) {
  int p = blockIdx.x * 256 + threadIdx.x;
  if (p >= NG_) return;
  int g = gate_perm(p);
  const float* wy = &W_ih[(long)g * IND_ + FEAT_];
  float s = 0.f;
  #pragma unroll 8
  for (int m = 0; m < MAN_; ++m) s += b_mu[m] * wy[m];
  bvec2[p] = b_ih[g] + b_hh[g] + s;
  nbm[p] = -s;
}

__global__ void out_t0(const float* __restrict__ y0, float* __restrict__ out) {
  int i = blockIdx.x * 256 + threadIdx.x;       // over B_*MAN_
  int b = i >> 7, m = i & 127;
  out[(long)b * (T_ * MAN_) + m] = y0[i];
}

// ---------------- generic bf16 MFMA GEMM: C = A @ W^T (+bias[col]) (+addmat) ----------
// (prep / prologue / final GEMMs; R2-proven single-buffer 2-barrier structure)
// SMODE: 0 fp32 store; 1 bf16 store; 2 decoder scatter; 3 fused cell (q addmat/addmat2);
//        4 bf16 q-layout store. AMODE: 0 none; 3 fp32 addmat[gate_perm(row)*N+col];
//        5 bf16 q-layout addmat.
template<int SMODE, int AMODE>
__global__ __launch_bounds__(256, 2)
void gemm_bt(const unsigned short* __restrict__ A1, long lda1,
             const unsigned short* __restrict__ A2, long lda2, int K1,
             const unsigned short* __restrict__ W1, const unsigned short* __restrict__ W2,
             int N, int K,
             const float* __restrict__ bias,
             const void* __restrict__ addmat, const void* __restrict__ addmat2,
             void* __restrict__ outp, long ldo,
             float* __restrict__ cstate, unsigned short* __restrict__ hout)
{
  __shared__ unsigned short As[128 * 64];
  __shared__ unsigned short Bs[128 * 64];
  const int tid = threadIdx.x, lane = tid & 63, wave = tid >> 6;
  const long bm = blockIdx.x, bn = blockIdx.y;

  f32x4 acc[4][4] = {};

  const int nkt = K >> 6;
  const int wm = wave >> 1, wn = wave & 1;
  const int lr = lane & 15, lq = lane >> 4;

  for (int kt = 0; kt < nkt; ++kt) {
    const int k0 = kt << 6;
    const unsigned short* Ab; long lda; const unsigned short* Wb; long ldw; int ko;
    if (k0 < K1) { Ab = A1; lda = lda1; Wb = W1; ldw = K1;      ko = k0; }
    else         { Ab = A2; lda = lda2; Wb = W2; ldw = K - K1;  ko = k0 - K1; }
    __syncthreads();
    #pragma unroll
    for (int it = 0; it < 4; ++it) {
      const int c0 = it * 256 + wave * 64;
      const int c = c0 + lane;
      const int row = c >> 3, sub = c & 7;
      gload16(Ab + (bm * 128 + row) * lda + ko + sub * 8, &As[c0 * 8]);
      gload16(Wb + (bn * 128 + row) * ldw + ko + sub * 8, &Bs[c0 * 8]);
    }
    __syncthreads();
    #pragma unroll
    for (int kk = 0; kk < 2; ++kk) {
      short8 av[4], bv[4];
      const int lk = kk * 32 + lq * 8;
      #pragma unroll
      for (int m = 0; m < 4; ++m)
        av[m] = *reinterpret_cast<const short8*>(&As[(wm * 64 + m * 16 + lr) * 64 + lk]);
      #pragma unroll
      for (int n = 0; n < 4; ++n)
        bv[n] = *reinterpret_cast<const short8*>(&Bs[(wn * 64 + n * 16 + lr) * 64 + lk]);
      #pragma unroll
      for (int m = 0; m < 4; ++m)
        #pragma unroll
        for (int n = 0; n < 4; ++n)
          acc[m][n] = __builtin_amdgcn_mfma_f32_16x16x32_bf16(av[m], bv[n], acc[m][n], 0, 0, 0);
    }
  }

  const long grp = bn * 128 + wn * 64;

  if constexpr (SMODE == 3) {
    const int hcol = (int)bn * 32 + wn * 16 + lr;
    #pragma unroll
    for (int m = 0; m < 4; ++m) {
      #pragma unroll
      for (int r2 = 0; r2 < 4; ++r2) {
        const long row = bm * 128 + wm * 64 + m * 16 + lq * 4 + r2;
        const long qbase = row * (long)N + grp + lr * 4;
        ushort4 tq = *reinterpret_cast<const ushort4*>(
            &((const unsigned short*)addmat2)[qbase]);
        float gi = acc[m][0][r2] + b2f(tq.x);
        float gf = acc[m][1][r2] + b2f(tq.y);
        float gg = acc[m][2][r2] + b2f(tq.z);
        float go = acc[m][3][r2] + b2f(tq.w);
        if (addmat) {
          ushort4 gq = *reinterpret_cast<const ushort4*>(
              &((const unsigned short*)addmat)[qbase]);
          gi += b2f(gq.x); gf += b2f(gq.y); gg += b2f(gq.z); go += b2f(gq.w);
        }
        const long ci = row * HID_ + hcol;
        float c = cstate[ci];
        c = sigmoidf_(gf) * c + sigmoidf_(gi) * tanh_fast(gg);
        cstate[ci] = c;
        hout[ci] = f2b(sigmoidf_(go) * tanh_fast(c));
      }
    }
    return;
  }

  if constexpr (SMODE == 4) {
    #pragma unroll
    for (int m = 0; m < 4; ++m) {
      #pragma unroll
      for (int r2 = 0; r2 < 4; ++r2) {
        const long row = bm * 128 + wm * 64 + m * 16 + lq * 4 + r2;
        float v[4];
        #pragma unroll
        for (int n = 0; n < 4; ++n) {
          const long col = grp + n * 16 + lr;
          v[n] = acc[m][n][r2] + (bias ? bias[col] : 0.0f);
        }
        if constexpr (AMODE == 5) {
          ushort4 a4 = *reinterpret_cast<const ushort4*>(
              &((const unsigned short*)addmat)[row * (long)N + grp + lr * 4]);
          v[0] += b2f(a4.x); v[1] += b2f(a4.y); v[2] += b2f(a4.z); v[3] += b2f(a4.w);
        }
        ushort4 o;
        o.x = f2b(v[0]); o.y = f2b(v[1]); o.z = f2b(v[2]); o.w = f2b(v[3]);
        *reinterpret_cast<ushort4*>(
            &reinterpret_cast<unsigned short*>(outp)[row * ldo + grp + lr * 4]) = o;
      }
    }
    return;
  }

  // standard epilogues
  #pragma unroll
  for (int m = 0; m < 4; ++m) {
    #pragma unroll
    for (int n = 0; n < 4; ++n) {
      const long col = grp + n * 16 + lr;
      const float bvv = bias ? bias[col] : 0.0f;
      #pragma unroll
      for (int r2 = 0; r2 < 4; ++r2) {
        const long row = bm * 128 + wm * 64 + m * 16 + lq * 4 + r2;
        float v = acc[m][n][r2] + bvv;
        if constexpr (AMODE == 3) v += ((const float*)addmat)[(long)gate_perm((int)row) * N + col];
        if constexpr (SMODE == 0) {
          reinterpret_cast<float*>(outp)[row * ldo + col] = v;
        } else if constexpr (SMODE == 1) {
          reinterpret_cast<unsigned short*>(outp)[row * ldo + col] = f2b(v);
        } else {
          const long bb = row & 1023, tt = (row >> 10) + 1;
          reinterpret_cast<float*>(outp)[bb * (T_ * MAN_) + tt * MAN_ + col] = v;
        }
      }
    }
  }
}

// ---------------- fused step kernel: h-GEMM+cell  ∥  xg slab for step t+1 ----------------
// Grid 1024 (512 step-blocks + 512 xg-blocks; last step: 512, step-only). The xg role
// (x_{t+1} @ Wx^T, K=1024, q-layout store into a 2-slab ring) is independent of the
// step's output and fills the step role's barrier-drain stalls (4 blocks/CU co-resident).
// Both roles use the m204 flat%8=XCD swizzle (XCD k owns bn in [8k,8k+8)).
__global__ __launch_bounds__(256, 2)
void step_fused(const unsigned short* __restrict__ Whh,
                const unsigned short* __restrict__ Wx,
                const unsigned short* __restrict__ Xt1,    // Xtm slab t+1 (or null)
                const unsigned short* __restrict__ xg_rd,  // ring slab t   (q-layout)
                unsigned short* __restrict__ xg_wr,        // ring slab t+1 (or null)
                const unsigned short* __restrict__ TBq,    // q-layout TB for step t
                const unsigned short* __restrict__ hprev,
                unsigned short* __restrict__ hout,
                float* __restrict__ cstate)
{
  __shared__ unsigned short As[128 * 64];
  __shared__ unsigned short Bs[128 * 64];
  const int tid = threadIdx.x, lane = tid & 63, wave = tid >> 6;
  const int flat = (int)blockIdx.x;
  const bool isStep = flat < 512;
  const int f = isStep ? flat : flat - 512;
  const int j = f >> 3;
  const long bm = j >> 3;                       // 8 values
  const long bn = (long)(f & 7) * 8 + (j & 7);  // 64 values, XCD-contiguous
  const int wm = wave >> 1, wn = wave & 1;
  const int lr = lane & 15, lq = lane >> 4;

  const unsigned short* Abase = isStep ? hprev : Xt1;
  const unsigned short* Wbase = isStep ? Whh : Wx;
  const long lda = isStep ? HID_ : FEAT_;       // == W row stride for both roles
  const int nkt = isStep ? (HID_ >> 6) : (FEAT_ >> 6);

  f32x4 acc[4][4] = {};

  for (int kt = 0; kt < nkt; ++kt) {
    const int ko = kt << 6;
    __syncthreads();
    #pragma unroll
    for (int it = 0; it < 4; ++it) {
      const int c0 = it * 256 + wave * 64;
      const int c = c0 + lane;
      const int row = c >> 3, sub = c & 7;
      gload16(Abase + (bm * 128 + row) * lda + ko + sub * 8, &As[c0 * 8]);
      gload16(Wbase + (bn * 128 + row) * lda + ko + sub * 8, &Bs[c0 * 8]);
    }
    __syncthreads();
    #pragma unroll
    for (int kk = 0; kk < 2; ++kk) {
      short8 av[4], bv[4];
      const int lk = kk * 32 + lq * 8;
      #pragma unroll
      for (int m = 0; m < 4; ++m)
        av[m] = *reinterpret_cast<const short8*>(&As[(wm * 64 + m * 16 + lr) * 64 + lk]);
      #pragma unroll
      for (int n = 0; n < 4; ++n)
        bv[n] = *reinterpret_cast<const short8*>(&Bs[(wn * 64 + n * 16 + lr) * 64 + lk]);
      #pragma unroll
      for (int m = 0; m < 4; ++m)
        #pragma unroll
        for (int n = 0; n < 4; ++n)
          acc[m][n] = __builtin_amdgcn_mfma_f32_16x16x32_bf16(av[m], bv[n], acc[m][n], 0, 0, 0);
    }
  }

  const long grp = bn * 128 + wn * 64;

  if (isStep) {
    // fused LSTM cell: n=0..3 fragments are i,f,g,o for h = bn*32+wn*16+lr
    const int hcol = (int)bn * 32 + wn * 16 + lr;
    #pragma unroll
    for (int m = 0; m < 4; ++m) {
      #pragma unroll
      for (int r2 = 0; r2 < 4; ++r2) {
        const long row = bm * 128 + wm * 64 + m * 16 + lq * 4 + r2;
        const long qbase = row * (long)NG_ + grp + lr * 4;
        ushort4 gq = *reinterpret_cast<const ushort4*>(&xg_rd[qbase]);
        ushort4 tq = *reinterpret_cast<const ushort4*>(&TBq[qbase]);
        float gi = acc[m][0][r2] + b2f(gq.x) + b2f(tq.x);
        float gf = acc[m][1][r2] + b2f(gq.y) + b2f(tq.y);
        float gg = acc[m][2][r2] + b2f(gq.z) + b2f(tq.z);
        float go = acc[m][3][r2] + b2f(gq.w) + b2f(tq.w);
        const long ci = row * HID_ + hcol;
        float c = cstate[ci];
        c = sigmoidf_(gf) * c + sigmoidf_(gi) * tanh_fast(gg);
        cstate[ci] = c;
        hout[ci] = f2b(sigmoidf_(go) * tanh_fast(c));
      }
    }
  } else {
    // q-layout bf16 store of x_{t+1} gates into ring slab t+1
    #pragma unroll
    for (int m = 0; m < 4; ++m) {
      #pragma unroll
      for (int r2 = 0; r2 < 4; ++r2) {
        const long row = bm * 128 + wm * 64 + m * 16 + lq * 4 + r2;
        ushort4 o;
        o.x = f2b(acc[m][0][r2]); o.y = f2b(acc[m][1][r2]);
        o.z = f2b(acc[m][2][r2]); o.w = f2b(acc[m][3][r2]);
        *reinterpret_cast<ushort4*>(&xg_wr[row * (long)NG_ + grp + lr * 4]) = o;
      }
    }
  }
}

// ---------------- launcher ----------------
extern "C" void kernel_launch(void* const* d_in, const int* in_sizes, int n_in,
                              void* d_out, int out_size, void* d_ws, size_t ws_size,
                              hipStream_t stream) {
  const float* input_repr = (const float*)d_in[0];
  const float* time_enc   = (const float*)d_in[1];
  const float* y0         = (const float*)d_in[2];
  const float* W_ih       = (const float*)d_in[3];
  const float* b_ih       = (const float*)d_in[4];
  const float* W_hh       = (const float*)d_in[5];
  const float* b_hh       = (const float*)d_in[6];
  const float* W_mu       = (const float*)d_in[7];
  const float* b_mu       = (const float*)d_in[8];
  float* out = (float*)d_out;

  char* ws = (char*)d_ws;
  auto alloc = [&](size_t bytes) {
    char* p = ws; ws += (bytes + 255) & ~(size_t)255; return p;
  };
  unsigned short* Xtm    = (unsigned short*)alloc((size_t)T_ * B_ * FEAT_ * 2);   // 134 MB (time-major)
  unsigned short* hstore = (unsigned short*)alloc((size_t)T_ * B_ * HID_ * 2);    // 268 MB
  float*  cst   = (float*)alloc((size_t)B_ * HID_ * 4);                           // 8.4 MB
  unsigned short* TB2 = (unsigned short*)alloc((size_t)B_ * NG_ * 2);             // 16.8 MB (bf16, q-layout)
  unsigned short* TB1 = (unsigned short*)alloc((size_t)B_ * NG_ * 2);             // 16.8 MB (q-layout)
  unsigned short* Whhf  = (unsigned short*)alloc((size_t)NG_ * HID_ * 2);         // 33.5 MB (perm rows)
  unsigned short* Wxbf  = (unsigned short*)alloc((size_t)NG_ * FEAT_ * 2);        // 16.8 MB (perm rows)
  unsigned short* Wybf  = (unsigned short*)alloc((size_t)NG_ * MAN_ * 2);         // (perm rows)
  unsigned short* Wtebf = (unsigned short*)alloc((size_t)NG_ * TENC_ * 2);        // (perm rows)
  unsigned short* WmuT  = (unsigned short*)alloc((size_t)HID_ * MAN_ * 2);
  unsigned short* Wmubf = (unsigned short*)alloc((size_t)MAN_ * HID_ * 2);
  unsigned short* tebf  = (unsigned short*)alloc((size_t)B_ * TENC_ * 2);
  unsigned short* y0bf  = (unsigned short*)alloc((size_t)B_ * MAN_ * 2);
  float* bvec2 = (float*)alloc(NG_ * 4);
  float* nbm   = (float*)alloc(NG_ * 4);
  size_t base_bytes = (size_t)(ws - (char*)d_ws);
  // xg 2-slab ring (33.6 MB), q-layout
  size_t xg_bytes = (size_t)2 * B_ * NG_ * 2;
  bool use_xg = (base_bytes + xg_bytes + 4096) <= ws_size;
  unsigned short* xgring = use_xg ? (unsigned short*)alloc(xg_bytes) : nullptr;

  // --- conversions / preps (all parallel work) ---
  pack_x_tm<<<B_ * T_, 256, 0, stream>>>(input_repr, Xtm);
  pack_wih<<<dim3(2, NG_), 256, 0, stream>>>(W_ih, Wxbf, Wybf, Wtebf);
  pack_bf16<<<dim3(2, MAN_), 256, 0, stream>>>(W_mu, HID_, 0, Wmubf, HID_);
  pack_bf16<<<dim3(1, B_), 256, 0, stream>>>(time_enc, TENC_, 0, tebf, TENC_);
  pack_bf16<<<dim3(1, B_), 256, 0, stream>>>(y0, MAN_, 0, y0bf, MAN_);
  transpose_to_bf16<<<1024, 256, 0, stream>>>(W_mu, WmuT);
  bias_prep<<<NG_ / 256, 256, 0, stream>>>(W_ih, b_ih, b_hh, b_mu, bvec2, nbm);
  zero_u32<<<(B_ * HID_ / 2 + 255) / 256, 256, 0, stream>>>((unsigned int*)hstore, (long)B_ * HID_ / 2); // h0 = 0
  zero_u32<<<(B_ * HID_ + 255) / 256, 256, 0, stream>>>((unsigned int*)cst, (long)B_ * HID_);            // c0 = 0
  out_t0<<<B_ * MAN_ / 256, 256, 0, stream>>>(y0, out);

  // Whhf = perm(W_hh) + permWy @ W_mu   (bf16, rows permuted)   M=NG_, N=HID_, K=MAN_
  gemm_bt<1, 3><<<dim3(NG_ / 128, HID_ / 128), 256, 0, stream>>>(
      Wybf, MAN_, Wybf, MAN_, MAN_, WmuT, WmuT, HID_, MAN_,
      nullptr, W_hh, nullptr, Whhf, HID_, nullptr, nullptr);
  // TB2 = q(te @ permWte^T + bvec2)                M=B_, N=NG_, K=TENC_ (bf16 q-layout)
  gemm_bt<4, 0><<<dim3(B_ / 128, NG_ / 128), 256, 0, stream>>>(
      tebf, TENC_, tebf, TENC_, TENC_, Wtebf, Wtebf, NG_, TENC_,
      bvec2, nullptr, nullptr, TB2, NG_, nullptr, nullptr);
  // TB1 = q(y0 @ permWy^T + nbm) + TB2(q)          M=B_, N=NG_, K=MAN_ (bf16 q-layout)
  gemm_bt<4, 5><<<dim3(B_ / 128, NG_ / 128), 256, 0, stream>>>(
      y0bf, MAN_, y0bf, MAN_, MAN_, Wybf, Wybf, NG_, MAN_,
      nbm, TB2, nullptr, TB1, NG_, nullptr, nullptr);

  if (use_xg) {
    // prologue: xg slab for t=1 into ring[1]   (M=B_, K=1024, q-layout)
    gemm_bt<4, 0><<<dim3(B_ / 128, NG_ / 128), 256, 0, stream>>>(
        Xtm + (long)B_ * FEAT_, FEAT_, Xtm, FEAT_, 1024,
        Wxbf, Wxbf, NG_, 1024,
        nullptr, nullptr, nullptr, xgring + (size_t)B_ * NG_, NG_, nullptr, nullptr);

    // 63 fused steps: h-GEMM+cell (slab t) ∥ xg GEMM (slab t+1)
    for (int t = 1; t < T_; ++t) {
      const bool hasxg = (t + 1 < T_);
      step_fused<<<hasxg ? 1024 : 512, 256, 0, stream>>>(
          Whhf, Wxbf,
          hasxg ? Xtm + (long)(t + 1) * B_ * FEAT_ : nullptr,
          xgring + (size_t)(t & 1) * B_ * NG_,
          hasxg ? xgring + (size_t)((t + 1) & 1) * B_ * NG_ : nullptr,
          (t == 1 ? TB1 : TB2),
          hstore + (long)(t - 1) * B_ * HID_,
          hstore + (long)t * B_ * HID_,
          cst);
    }
  } else {
    // fallback: per-step K=3072 two-region GEMM + fused cell (TB via q-addmat2)
    for (int t = 1; t < T_; ++t) {
      const unsigned short* A1 = Xtm + (long)t * B_ * FEAT_;
      const unsigned short* A2 = hstore + (long)(t - 1) * B_ * HID_;
      gemm_bt<3, 0><<<dim3(B_ / 128, NG_ / 128), 256, 0, stream>>>(
          A1, FEAT_, A2, HID_, FEAT_,
          Wxbf, Whhf, NG_, FEAT_ + HID_,
          nullptr, nullptr, (t == 1 ? TB1 : TB2), nullptr, 0,
          cst, hstore + (long)t * B_ * HID_);
    }
  }

  // --- all outputs y_t = h_t @ W_mu^T + b_mu in one GEMM, scattered into (B,T,MAN) ---
  gemm_bt<2, 0><<<dim3((T_ - 1) * B_ / 128, MAN_ / 128), 256, 0, stream>>>(
      hstore + (long)B_ * HID_, HID_, hstore + (long)B_ * HID_, HID_, HID_,
      Wmubf, Wmubf, MAN_, HID_,
      b_mu, nullptr, nullptr, out, 0, nullptr, nullptr);
}